// Round 1
// baseline (3949.975 us; speedup 1.0000x reference)
//
#include <hip/hip_runtime.h>
#include <hip/hip_bf16.h>
#include <stdint.h>

// GNN_758: stacked RelGraphConv x2.  N=50000 nodes, E=1.6M edges, D=128, R=20.
// Strategy: aggregate-then-transform. agg[dst] = sum_r (sum_{e: rel r -> dst} h[src]) @ W[r]
// Per 16-dst tile, pre-aggregate S lives in LDS; transform via bf16 MFMA.
// Self-loop (h @ loop_w) folded in as relation 20. Bias in epilogue.

#define NN 50000
#define NE 1600000
#define DIM 128
#define NREL 20
#define NRELP 21        // +1 pseudo-relation for self loop
#define TILE 16
#define PADK 133        // 128 + 5: breaks LDS bank aliasing on A-frag reads
#define PACKED_ELEMS (2 * NRELP * 4 * 8 * 64 * 8)   // l,r,kstep,nchunk,lane,j = 688128

typedef __attribute__((ext_vector_type(8))) short short8;
typedef __attribute__((ext_vector_type(4))) float f32x4;

__device__ __forceinline__ unsigned short f32_to_bf16_raw(float f) {
  union { float f; unsigned u; } c; c.f = f;
  unsigned u = c.u;
  unsigned r = (u + 0x7fffu + ((u >> 16) & 1u)) >> 16;  // RNE
  return (unsigned short)r;
}
__device__ __forceinline__ float bf16_raw_to_f32(unsigned short s) {
  union { unsigned u; float f; } c; c.u = ((unsigned)s) << 16;
  return c.f;
}

// ---------------- conversion: fp32 -> bf16 (x4 vectorized) ----------------
__global__ void cvt_bf16_kernel(const float* __restrict__ in,
                                unsigned short* __restrict__ out, int n4) {
  int i = blockIdx.x * 256 + threadIdx.x;
  if (i < n4) {
    float4 f = ((const float4*)in)[i];
    short4 o;
    o.x = (short)f32_to_bf16_raw(f.x);
    o.y = (short)f32_to_bf16_raw(f.y);
    o.z = (short)f32_to_bf16_raw(f.z);
    o.w = (short)f32_to_bf16_raw(f.w);
    ((short4*)out)[i] = o;
  }
}

// ---------------- pack W (+loop_w as rel 20) into B-fragment order ----------------
// B-operand layout assumption (mfma_f32_16x16x32_bf16): lane holds
// B[k = (lane>>4)*8 + j][n = lane&15], j=0..7.   <-- if output comes back
// tile-transposed, swap k<->n here (one line).
// WP flat index: ((((l*21 + r)*4 + ks)*8 + nc)*64 + lane)*8 + j
__global__ void pack_w_kernel(const float* __restrict__ W,
                              const float* __restrict__ loop_w,
                              unsigned short* __restrict__ WP) {
  int idx = blockIdx.x * 256 + threadIdx.x;
  if (idx >= PACKED_ELEMS) return;
  int j = idx & 7;       int t = idx >> 3;
  int lane = t & 63;     t >>= 6;
  int nc = t & 7;        t >>= 3;
  int ks = t & 3;        t >>= 2;
  int r = t % NRELP;     int l = t / NRELP;
  int k = ks * 32 + (lane >> 4) * 8 + j;
  int n = nc * 16 + (lane & 15);
  float v = (r < NREL) ? W[(((size_t)l * NREL + r) * DIM + k) * DIM + n]
                       : loop_w[((size_t)l * DIM + k) * DIM + n];
  WP[idx] = f32_to_bf16_raw(v);
}

// ---------------- CSR-by-dst build ----------------
__global__ void hist_kernel(const int* __restrict__ dst,
                            unsigned int* __restrict__ counts, int n) {
  int i = blockIdx.x * 256 + threadIdx.x;
  if (i < n) atomicAdd(&counts[dst[i]], 1u);
}

__global__ void scan_kernel(const unsigned int* __restrict__ counts,
                            unsigned int* __restrict__ row_ofs,
                            unsigned int* __restrict__ cursor) {
  __shared__ unsigned int buf[1024];
  __shared__ unsigned int carry;
  int t = threadIdx.x;
  if (t == 0) carry = 0;
  __syncthreads();
  for (int base = 0; base < NN; base += 1024) {
    int i = base + t;
    unsigned int v = (i < NN) ? counts[i] : 0u;
    buf[t] = v;
    __syncthreads();
    for (int d = 1; d < 1024; d <<= 1) {
      unsigned int add = (t >= d) ? buf[t - d] : 0u;
      __syncthreads();
      buf[t] += add;
      __syncthreads();
    }
    unsigned int excl = buf[t] - v + carry;
    if (i < NN) { row_ofs[i] = excl; cursor[i] = excl; }
    __syncthreads();
    if (t == 1023) carry += buf[1023];
    __syncthreads();
  }
  if (t == 0) row_ofs[NN] = carry;
}

__global__ void scatter_kernel(const int* __restrict__ src, const int* __restrict__ dst,
                               const int* __restrict__ et,
                               unsigned int* __restrict__ cursor,
                               unsigned int* __restrict__ sorted, int n) {
  int i = blockIdx.x * 256 + threadIdx.x;
  if (i < n) {
    unsigned int pos = atomicAdd(&cursor[dst[i]], 1u);
    sorted[pos] = (unsigned int)src[i] | ((unsigned int)et[i] << 16);  // N<65536
  }
}

// ---------------- fused RGCN layer ----------------
// grid = N/16 = 3125 blocks, 256 threads (4 waves).
// LDS S[16][6][PADK] fp32 ~ 51 KB -> 3 blocks/CU.
__global__ __launch_bounds__(256) void rgcn_layer_kernel(
    const unsigned short* __restrict__ hb,    // [N,128] bf16 of current h
    const unsigned short* __restrict__ WP,    // packed weights
    const float* __restrict__ bias,           // [128] this layer
    int layer,
    const unsigned int* __restrict__ row_ofs, // [N+1]
    const unsigned int* __restrict__ sorted,  // [E] packed (src | et<<16), dst-sorted
    float* __restrict__ out)                  // [N,128] fp32
{
  __shared__ float S[TILE][6][PADK];
  __shared__ unsigned int ofs_l[TILE + 1];

  const int tid  = threadIdx.x;
  const int lane = tid & 63;
  const int w    = tid >> 6;        // wave 0..3
  const int quad = lane >> 4;
  const int dst_base = blockIdx.x * TILE;

  if (tid <= TILE) ofs_l[tid] = row_ofs[dst_base + tid];
  __syncthreads();
  const int e_begin = (int)ofs_l[0];
  const int e_end   = (int)ofs_l[TILE];

  f32x4 acc0 = {0.f, 0.f, 0.f, 0.f};
  f32x4 acc1 = {0.f, 0.f, 0.f, 0.f};

  const int k_lane = tid & 127;     // element within a D=128 row
  const int half   = tid >> 7;      // 0 or 1: which edge of a pair

  for (int c = 0; c < 4; ++c) {
    const int rbase = c * 5;
    const int rc = (c == 3) ? 6 : 5;   // chunk 3: rels 15..19 + self-loop slot 5

    // zero S
    for (int i = tid; i < TILE * 6 * PADK; i += 256) ((float*)S)[i] = 0.f;
    __syncthreads();

    // self-loop: S[d][5][k] = h[dst_base+d][k]  (rel 20, chunk 3 only)
    if (c == 3) {
      for (int d = half; d < TILE; d += 2)
        S[d][5][k_lane] = bf16_raw_to_f32(hb[(dst_base + d) * DIM + k_lane]);
    }

    // phase 1: scatter h[src] into per-(dst,rel) LDS buckets
    for (int e = e_begin + half; e < e_end; e += 2) {
      unsigned int pk = sorted[e];
      int rl = (int)(pk >> 16) - rbase;
      if ((unsigned)rl < 5u) {            // real rels only (0..4 within chunk)
        int d = 0;                        // find dst_local: ofs_l[d] <= e < ofs_l[d+1]
        if (ofs_l[d + 8] <= (unsigned)e) d += 8;
        if (ofs_l[d + 4] <= (unsigned)e) d += 4;
        if (ofs_l[d + 2] <= (unsigned)e) d += 2;
        if (ofs_l[d + 1] <= (unsigned)e) d += 1;
        int src = (int)(pk & 0xffffu);
        float v = bf16_raw_to_f32(hb[src * DIM + k_lane]);
        atomicAdd(&S[d][rl][k_lane], v);
      }
    }
    __syncthreads();

    // phase 2: agg_tile += S[:,rl,:] @ W[rel]   (16x16x32 bf16 MFMA)
    for (int rl = 0; rl < rc; ++rl) {
      const int r = rbase + rl;
      const float* sp = &S[lane & 15][rl][0];
      const size_t wb = (((size_t)(layer * NRELP + r)) * 4);
      for (int ks = 0; ks < 4; ++ks) {
        short8 a;
        const float* ap = sp + ks * 32 + quad * 8;
#pragma unroll
        for (int j = 0; j < 8; ++j) a[j] = (short)f32_to_bf16_raw(ap[j]);
        const size_t bb = ((wb + ks) * 8);
        short8 b0 = *(const short8*)(WP + ((bb + w    ) * 64 + lane) * 8);
        short8 b1 = *(const short8*)(WP + ((bb + w + 4) * 64 + lane) * 8);
        acc0 = __builtin_amdgcn_mfma_f32_16x16x32_bf16(a, b0, acc0, 0, 0, 0);
        acc1 = __builtin_amdgcn_mfma_f32_16x16x32_bf16(a, b1, acc1, 0, 0, 0);
      }
    }
    __syncthreads();
  }

  // epilogue: + bias, store. C/D layout: col=lane&15, row=quad*4+reg (m89-verified)
  const int col0 = w * 16 + (lane & 15);
  const int col1 = (w + 4) * 16 + (lane & 15);
  const float b0 = bias[col0], b1 = bias[col1];
#pragma unroll
  for (int i = 0; i < 4; ++i) {
    int row = dst_base + quad * 4 + i;
    out[row * DIM + col0] = acc0[i] + b0;
    out[row * DIM + col1] = acc1[i] + b1;
  }
}

// ---------------- launch ----------------
extern "C" void kernel_launch(void* const* d_in, const int* in_sizes, int n_in,
                              void* d_out, int out_size, void* d_ws, size_t ws_size,
                              hipStream_t stream) {
  const float* h0     = (const float*)d_in[0];   // [N,128]
  const float* W      = (const float*)d_in[1];   // [2,20,128,128]
  const float* loop_w = (const float*)d_in[2];   // [2,128,128]
  const float* bias   = (const float*)d_in[3];   // [2,128]
  const int* esrc     = (const int*)d_in[4];
  const int* edst     = (const int*)d_in[5];
  const int* etyp     = (const int*)d_in[6];
  float* out = (float*)d_out;

  char* ws = (char*)d_ws;
  size_t off = 0;
  auto alloc = [&](size_t bytes) -> void* {
    void* p = ws + off;
    off = (off + bytes + 255) & ~(size_t)255;
    return p;
  };
  unsigned short* h_bf16 = (unsigned short*)alloc((size_t)NN * DIM * 2);   // 12.8 MB
  unsigned short* WP     = (unsigned short*)alloc((size_t)PACKED_ELEMS * 2);
  float*          h1     = (float*)alloc((size_t)NN * DIM * 4);            // 25.6 MB
  unsigned int*   counts = (unsigned int*)alloc((size_t)NN * 4);
  unsigned int*   row_ofs= (unsigned int*)alloc((size_t)(NN + 1) * 4);
  unsigned int*   cursor = (unsigned int*)alloc((size_t)NN * 4);
  unsigned int*   sorted = (unsigned int*)alloc((size_t)NE * 4);           // 6.4 MB

  // CSR build (dst-sorted edge list)
  hipMemsetAsync(counts, 0, (size_t)NN * 4, stream);
  hist_kernel<<<NE / 256, 256, 0, stream>>>(edst, counts, NE);
  scan_kernel<<<1, 1024, 0, stream>>>(counts, row_ofs, cursor);
  scatter_kernel<<<NE / 256, 256, 0, stream>>>(esrc, edst, etyp, cursor, sorted, NE);

  // weight pack
  pack_w_kernel<<<(PACKED_ELEMS + 255) / 256, 256, 0, stream>>>(W, loop_w, WP);

  // layer 0
  cvt_bf16_kernel<<<(NN * DIM / 4 + 255) / 256, 256, 0, stream>>>(h0, h_bf16, NN * DIM / 4);
  rgcn_layer_kernel<<<NN / TILE, 256, 0, stream>>>(h_bf16, WP, bias, 0, row_ofs, sorted, h1);

  // layer 1
  cvt_bf16_kernel<<<(NN * DIM / 4 + 255) / 256, 256, 0, stream>>>(h1, h_bf16, NN * DIM / 4);
  rgcn_layer_kernel<<<NN / TILE, 256, 0, stream>>>(h_bf16, WP, bias + DIM, 1, row_ofs, sorted, out);
}

// Round 2
// 2533.180 us; speedup vs baseline: 1.5593x; 1.5593x over previous
//
#include <hip/hip_runtime.h>
#include <hip/hip_bf16.h>
#include <stdint.h>

// GNN_758: stacked RelGraphConv x2.  N=50000, E=1.6M, D=128, R=20.
// agg[dst] = sum_r (sum_{e in rel r -> dst} h[src]) @ W[r]; self-loop = rel 20.
// R1: edges pre-bucketed by (dst_tile, rel_chunk); phase1 4 edges/wave/iter with
// 16B vector loads; phase2 K-split across waves (A-frag reuse x8) + LDS reduction.

#define NN 50000
#define NE 1600000
#define DIM 128
#define NREL 20
#define NRELP 21
#define TILE 16
#define NTILE (NN / TILE)        // 3125
#define NBUCKET (NTILE * 4)      // 12500 (tile, rel-chunk)
#define STR_R 132                // rel slot stride in floats (16B aligned, +4 pad)
#define STR_D 812                // per-dst stride = 6*132 + 20 (bank scatter)
#define PACKED_ELEMS (2 * NRELP * 4 * 8 * 64 * 8)   // 688128

typedef __attribute__((ext_vector_type(8))) short short8;
typedef __attribute__((ext_vector_type(4))) float f32x4;

__device__ __forceinline__ unsigned short f32_to_bf16_raw(float f) {
  union { float f; unsigned u; } c; c.f = f;
  unsigned u = c.u;
  return (unsigned short)((u + 0x7fffu + ((u >> 16) & 1u)) >> 16);  // RNE
}
__device__ __forceinline__ float bf16_raw_to_f32(unsigned short s) {
  union { unsigned u; float f; } c; c.u = ((unsigned)s) << 16;
  return c.f;
}

// ---------------- fp32 -> bf16 (x4) ----------------
__global__ void cvt_bf16_kernel(const float* __restrict__ in,
                                unsigned short* __restrict__ out, int n4) {
  int i = blockIdx.x * 256 + threadIdx.x;
  if (i < n4) {
    float4 f = ((const float4*)in)[i];
    short4 o;
    o.x = (short)f32_to_bf16_raw(f.x);
    o.y = (short)f32_to_bf16_raw(f.y);
    o.z = (short)f32_to_bf16_raw(f.z);
    o.w = (short)f32_to_bf16_raw(f.w);
    ((short4*)out)[i] = o;
  }
}

// ---------------- pack W (+loop_w as rel 20) into B-fragment order ----------------
// WP flat: ((((l*21 + r)*4 + ks)*8 + nc)*64 + lane)*8 + j  (verified by R0 pass)
__global__ void pack_w_kernel(const float* __restrict__ W,
                              const float* __restrict__ loop_w,
                              unsigned short* __restrict__ WP) {
  int idx = blockIdx.x * 256 + threadIdx.x;
  if (idx >= PACKED_ELEMS) return;
  int j = idx & 7;       int t = idx >> 3;
  int lane = t & 63;     t >>= 6;
  int nc = t & 7;        t >>= 3;
  int ks = t & 3;        t >>= 2;
  int r = t % NRELP;     int l = t / NRELP;
  int k = ks * 32 + (lane >> 4) * 8 + j;
  int n = nc * 16 + (lane & 15);
  float v = (r < NREL) ? W[(((size_t)l * NREL + r) * DIM + k) * DIM + n]
                       : loop_w[((size_t)l * DIM + k) * DIM + n];
  WP[idx] = f32_to_bf16_raw(v);
}

// ---------------- edge bucketing by (dst_tile, rel_chunk) ----------------
__global__ void hist_kernel(const int* __restrict__ dst, const int* __restrict__ et,
                            unsigned int* __restrict__ counts, int n) {
  int i = blockIdx.x * 256 + threadIdx.x;
  if (i < n) {
    int b = (dst[i] >> 4) * 4 + (et[i] / 5);
    atomicAdd(&counts[b], 1u);
  }
}

__global__ void scan_kernel(const unsigned int* __restrict__ counts,
                            unsigned int* __restrict__ ofs,
                            unsigned int* __restrict__ cursor) {
  __shared__ unsigned int buf[1024];
  __shared__ unsigned int carry;
  int t = threadIdx.x;
  if (t == 0) carry = 0;
  __syncthreads();
  for (int base = 0; base < NBUCKET; base += 1024) {
    int i = base + t;
    unsigned int v = (i < NBUCKET) ? counts[i] : 0u;
    buf[t] = v;
    __syncthreads();
    for (int d = 1; d < 1024; d <<= 1) {
      unsigned int add = (t >= d) ? buf[t - d] : 0u;
      __syncthreads();
      buf[t] += add;
      __syncthreads();
    }
    unsigned int excl = buf[t] - v + carry;
    if (i < NBUCKET) { ofs[i] = excl; cursor[i] = excl; }
    __syncthreads();
    if (t == 1023) carry += buf[1023];
    __syncthreads();
  }
  if (t == 0) ofs[NBUCKET] = carry;
}

// pack: src(16b) | rel_local(3b)<<16 | dst_local(4b)<<19
__global__ void scatter_kernel(const int* __restrict__ src, const int* __restrict__ dst,
                               const int* __restrict__ et,
                               unsigned int* __restrict__ cursor,
                               unsigned int* __restrict__ epk, int n) {
  int i = blockIdx.x * 256 + threadIdx.x;
  if (i < n) {
    int d = dst[i], e = et[i];
    int b = (d >> 4) * 4 + (e / 5);
    unsigned int pos = atomicAdd(&cursor[b], 1u);
    epk[pos] = (unsigned int)src[i] | ((unsigned int)(e % 5) << 16)
             | ((unsigned int)(d & 15) << 19);
  }
}

// ---------------- fused RGCN layer ----------------
// 3125 blocks x 256 threads. LDS ~51 KB -> 3 blocks/CU.
__global__ __launch_bounds__(256) void rgcn_layer_kernel(
    const unsigned short* __restrict__ hb,    // [N,128] bf16
    const unsigned short* __restrict__ WP,    // packed weights
    const float* __restrict__ bias,           // [128] this layer
    int layer,
    const unsigned int* __restrict__ bofs,    // [NBUCKET+1]
    const unsigned int* __restrict__ epk,     // [E] packed, bucket-sorted
    float* __restrict__ out)                  // [N,128] fp32
{
  __shared__ __align__(16) float S[TILE][STR_D];   // 51968 B
  __shared__ unsigned int bofs_l[5];

  const int tid  = threadIdx.x;
  const int lane = tid & 63;
  const int w    = tid >> 6;        // wave 0..3 = k-chunk owner
  const int quad = lane >> 4;
  const int m    = lane & 15;
  const int dst_base = blockIdx.x * TILE;

  if (tid < 5) bofs_l[tid] = bofs[blockIdx.x * 4 + tid];

  f32x4 acc[8];
#pragma unroll
  for (int nc = 0; nc < 8; ++nc) acc[nc] = (f32x4){0.f, 0.f, 0.f, 0.f};

  for (int c = 0; c < 4; ++c) {
    const int rbase = c * 5;
    const int rc = (c == 3) ? 6 : 5;

    // zero atomic-target slots 0..4 (2560 float4 / 256 thr = 10 each)
    for (int t = tid; t < TILE * 5 * 32; t += 256) {
      int d = t / 160, rem = t - d * 160;
      int rl = rem >> 5, kq = rem & 31;
      *(float4*)&S[d][rl * STR_R + kq * 4] = (float4){0.f, 0.f, 0.f, 0.f};
    }
    // self-loop rows into slot 5 (chunk 3 only): one ushort8 per thread
    if (c == 3) {
      int d = tid >> 4, mm = tid & 15;
      short8 hv = *(const short8*)(hb + (size_t)(dst_base + d) * DIM + mm * 8);
      float4 f0, f1;
      f0.x = bf16_raw_to_f32((unsigned short)hv[0]);
      f0.y = bf16_raw_to_f32((unsigned short)hv[1]);
      f0.z = bf16_raw_to_f32((unsigned short)hv[2]);
      f0.w = bf16_raw_to_f32((unsigned short)hv[3]);
      f1.x = bf16_raw_to_f32((unsigned short)hv[4]);
      f1.y = bf16_raw_to_f32((unsigned short)hv[5]);
      f1.z = bf16_raw_to_f32((unsigned short)hv[6]);
      f1.w = bf16_raw_to_f32((unsigned short)hv[7]);
      *(float4*)&S[d][5 * STR_R + mm * 8]     = f0;
      *(float4*)&S[d][5 * STR_R + mm * 8 + 4] = f1;
    }
    __syncthreads();

    // phase 1: 4 edges per wave per iter; 16 lanes x ushort8 per edge row
    {
      const int cbeg = (int)bofs_l[c], cend = (int)bofs_l[c + 1];
      const int g = quad;                       // edge-group within wave
      for (int e = cbeg + w * 4 + g; e < cend; e += 16) {
        unsigned int pk = epk[e];
        int src = (int)(pk & 0xffffu);
        int rl  = (int)((pk >> 16) & 7u);
        int d   = (int)((pk >> 19) & 15u);
        short8 hv = *(const short8*)(hb + (size_t)src * DIM + m * 8);
        float* base = &S[d][rl * STR_R + m * 8];
#pragma unroll
        for (int jj = 0; jj < 8; ++jj) {
          int j = (jj + m) & 7;                 // rotate: ~2-way banks
          atomicAdd(base + j, bf16_raw_to_f32((unsigned short)hv[j]));
        }
      }
    }
    __syncthreads();

    // phase 2: K-split. wave w owns k in [32w, 32w+32); A-frag reused for 8 nc.
    for (int rl = 0; rl < rc; ++rl) {
      const int r = rbase + rl;
      const float* ap = &S[m][rl * STR_R + w * 32 + quad * 8];
      float4 f0 = *(const float4*)ap;
      float4 f1 = *(const float4*)(ap + 4);
      short8 a;
      a[0] = (short)f32_to_bf16_raw(f0.x);
      a[1] = (short)f32_to_bf16_raw(f0.y);
      a[2] = (short)f32_to_bf16_raw(f0.z);
      a[3] = (short)f32_to_bf16_raw(f0.w);
      a[4] = (short)f32_to_bf16_raw(f1.x);
      a[5] = (short)f32_to_bf16_raw(f1.y);
      a[6] = (short)f32_to_bf16_raw(f1.z);
      a[7] = (short)f32_to_bf16_raw(f1.w);
      const unsigned short* bp =
          WP + ((((size_t)(layer * NRELP + r) * 4 + w) * 8) * 64 + lane) * 8;
#pragma unroll
      for (int nc = 0; nc < 8; ++nc) {
        short8 b = *(const short8*)(bp + (size_t)nc * 64 * 8);
        acc[nc] = __builtin_amdgcn_mfma_f32_16x16x32_bf16(a, b, acc[nc], 0, 0, 0);
      }
    }
    __syncthreads();
  }

  // cross-wave K-reduction through LDS. red[w][row16][132] = 33792 B (reuse S).
  float* red = &S[0][0];
#pragma unroll
  for (int nc = 0; nc < 8; ++nc)
#pragma unroll
    for (int i = 0; i < 4; ++i)
      red[w * (16 * 132) + (quad * 4 + i) * 132 + nc * 16 + m] = acc[nc][i];
  __syncthreads();

  {
    int row = tid >> 4, cb = (tid & 15) * 8;
    float4 b0 = *(const float4*)(bias + cb);
    float4 b1 = *(const float4*)(bias + cb + 4);
    float o[8];
#pragma unroll
    for (int j = 0; j < 8; ++j) {
      int col = cb + j;
      o[j] = red[0 * 2112 + row * 132 + col] + red[1 * 2112 + row * 132 + col]
           + red[2 * 2112 + row * 132 + col] + red[3 * 2112 + row * 132 + col];
    }
    o[0] += b0.x; o[1] += b0.y; o[2] += b0.z; o[3] += b0.w;
    o[4] += b1.x; o[5] += b1.y; o[6] += b1.z; o[7] += b1.w;
    float* op = out + (size_t)(dst_base + row) * DIM + cb;
    *(float4*)op       = (float4){o[0], o[1], o[2], o[3]};
    *(float4*)(op + 4) = (float4){o[4], o[5], o[6], o[7]};
  }
}

// ---------------- launch ----------------
extern "C" void kernel_launch(void* const* d_in, const int* in_sizes, int n_in,
                              void* d_out, int out_size, void* d_ws, size_t ws_size,
                              hipStream_t stream) {
  const float* h0     = (const float*)d_in[0];
  const float* W      = (const float*)d_in[1];
  const float* loop_w = (const float*)d_in[2];
  const float* bias   = (const float*)d_in[3];
  const int* esrc     = (const int*)d_in[4];
  const int* edst     = (const int*)d_in[5];
  const int* etyp     = (const int*)d_in[6];
  float* out = (float*)d_out;

  char* ws = (char*)d_ws;
  size_t off = 0;
  auto alloc = [&](size_t bytes) -> void* {
    void* p = ws + off;
    off = (off + bytes + 255) & ~(size_t)255;
    return p;
  };
  unsigned short* h_bf16 = (unsigned short*)alloc((size_t)NN * DIM * 2);
  unsigned short* WP     = (unsigned short*)alloc((size_t)PACKED_ELEMS * 2);
  float*          h1     = (float*)alloc((size_t)NN * DIM * 4);
  unsigned int*   counts = (unsigned int*)alloc((size_t)NBUCKET * 4);
  unsigned int*   bofs   = (unsigned int*)alloc((size_t)(NBUCKET + 1) * 4);
  unsigned int*   cursor = (unsigned int*)alloc((size_t)NBUCKET * 4);
  unsigned int*   epk    = (unsigned int*)alloc((size_t)NE * 4);

  hipMemsetAsync(counts, 0, (size_t)NBUCKET * 4, stream);
  hist_kernel<<<NE / 256, 256, 0, stream>>>(edst, etyp, counts, NE);
  scan_kernel<<<1, 1024, 0, stream>>>(counts, bofs, cursor);
  scatter_kernel<<<NE / 256, 256, 0, stream>>>(esrc, edst, etyp, cursor, epk, NE);

  pack_w_kernel<<<(PACKED_ELEMS + 255) / 256, 256, 0, stream>>>(W, loop_w, WP);

  cvt_bf16_kernel<<<(NN * DIM / 4 + 255) / 256, 256, 0, stream>>>(h0, h_bf16, NN * DIM / 4);
  rgcn_layer_kernel<<<NTILE, 256, 0, stream>>>(h_bf16, WP, bias, 0, bofs, epk, h1);

  cvt_bf16_kernel<<<(NN * DIM / 4 + 255) / 256, 256, 0, stream>>>(h1, h_bf16, NN * DIM / 4);
  rgcn_layer_kernel<<<NTILE, 256, 0, stream>>>(h_bf16, WP, bias + DIM, 1, bofs, epk, out);
}